// Round 18
// baseline (158.195 us; speedup 1.0000x reference)
//
#include <hip/hip_runtime.h>
#include <hip/hip_fp16.h>
#include <math.h>

#define Cc 128
#define Hh 128
#define Ww 128
#define Bb 8
#define HW 16384
#define NPIX 131072   // B*H*W
#define NOFF 18

typedef unsigned int u32;
typedef _Float16 half8 __attribute__((ext_vector_type(8)));
typedef __attribute__((ext_vector_type(16))) float f32x16;

static __device__ __forceinline__ u32 pack2h(float a, float b){
  __half2 h = __floats2half2_rn(a, b);
  return *(u32*)&h;
}

// ---------------- K0: pack B-fragments (f16) + w_dw packed half2 [k][cpair] ----------------
__global__ __launch_bounds__(256) void k_repack(const float* __restrict__ w_off, const float* __restrict__ w_dw,
                                                u32* __restrict__ wBf, u32* __restrict__ wdt_h){
  int i = blockIdx.x*256 + threadIdx.x;
  if (i < 72*64*4){
    int step = i >> 8;
    int r    = i & 255;
    int lane = r >> 2;
    int q    = r & 3;
    int tap  = step / 8, chunk = step % 8;
    int o    = lane & 31, half = lane >> 5;
    int c0   = chunk*16 + half*8 + 2*q;
    float v0 = (o < NOFF) ? w_off[(size_t)(o*Cc + c0    )*9 + tap] : 0.f;
    float v1 = (o < NOFF) ? w_off[(size_t)(o*Cc + c0 + 1)*9 + tap] : 0.f;
    wBf[i] = pack2h(v0, v1);
  }
  int j = i - 72*64*4;
  if (j >= 0 && j < 9*64){
    int cp = j & 63; int k = j >> 6;
    wdt_h[j] = pack2h(w_dw[(2*cp)*9 + k], w_dw[(2*cp+1)*9 + k]);
  }
}

// ---------------- K_tx: transpose x NCHW -> NHWC, f16-packed (2 ch per u32) ----------------
__global__ __launch_bounds__(256) void k_tx(const float* __restrict__ x, u32* __restrict__ xt16){
  __shared__ float t[128][65];
  int tid = threadIdx.x;
  int b   = blockIdx.x >> 8;
  int hw0 = (blockIdx.x & 255) << 6;
  int lane = tid & 63, wg = tid >> 6;
  const float* xb = x + (size_t)b*Cc*HW;
  #pragma unroll
  for (int k=0;k<32;k++){
    int c = wg + k*4;
    t[c][lane] = xb[(size_t)c*HW + hw0 + lane];
  }
  __syncthreads();
  u32* ob = xt16 + ((size_t)b*HW + hw0)*64;
  int cpair = tid & 63, grp = tid >> 6;
  #pragma unroll
  for (int k=0;k<16;k++){
    int hwl = grp + k*4;
    ob[(size_t)hwl*64 + cpair] = pack2h(t[cpair*2][hwl], t[cpair*2+1][hwl]);
  }
}

// ---------------- K1: offset conv via f16 MFMA; half-row blocks, K-split waves ----------------
// grid 2048 = [b(8)][h(128)][wh(2)]; block 256 = 4 waves = (mw in {0,1}) x (kh in {0,1}).
// Rotating 68-px stage buffer (17.7 KB) per row-phase; each wave does 3 dx-taps x 4 chunks
// of its K-half per phase (36 MFMA total). piv summed across kh via barrier-ordered add.
__global__ __launch_bounds__(256) void k_offset_mfma(const u32* __restrict__ xt, const u32* __restrict__ wBf,
                                                     const float* __restrict__ b_off, u32* __restrict__ recs){
  __shared__ u32 xl[68][65];             // 17.7 KB
  __shared__ float pivf[64][21];         // 5.4 KB
  int tid = threadIdx.x, lane = tid & 63, wv = tid >> 6;
  int mw = wv & 1, kh = wv >> 1;
  int b  = blockIdx.x >> 8;
  int rm = blockIdx.x & 255;
  int h  = rm >> 1, wh = rm & 1;
  int row = lane & 31, half = lane >> 5;
  int l = mw*32 + row;                   // local px in half-row
  int w = wh*64 + l;                     // image col

  const u32* xb = xt + (size_t)b*HW*64;
  const uint4* wb = (const uint4*)wBf;
  const u32* xl0 = &xl[0][0];

  f32x16 accE, accO;
  #pragma unroll
  for (int i=0;i<16;i++){ accE[i]=0.f; accO[i]=0.f; }

  int w0c = wh*64 - 2;

  #pragma unroll 1
  for (int r=0; r<3; r++){
    int hh = h + r - 1;
    int hc = min(max(hh,0),Hh-1);
    __syncthreads();                     // prev phase readers done
    for (int i=tid; i<68*16; i+=256){
      int q = i & 15, p = i >> 4;
      int gc = min(max(w0c + p, 0), Ww-1);
      *(uint4*)&xl[p][q*4] = *(const uint4*)(xb + ((size_t)(hc*Ww + gc))*64 + q*4);
    }
    __syncthreads();
    bool rowv = (hh>=0)&&(hh<Hh);
    #pragma unroll
    for (int dx=0; dx<3; dx++){
      int t = r*3 + dx;
      int wt = w + dx - 1;
      bool v = rowv && (wt>=0)&&(wt<Ww);
      int base = (l + dx + 1)*65 + half*4;           // p = l+dx+1
      #pragma unroll
      for (int ch=0; ch<4; ch++){
        uint4 a = *(const uint4*)(xl0 + base + (kh*4+ch)*8);
        if (!v){ a.x=0u; a.y=0u; a.z=0u; a.w=0u; }
        uint4 bf = wb[(t*8 + kh*4 + ch)*64 + lane];
        if (ch & 1) accO = __builtin_amdgcn_mfma_f32_32x32x16_f16(*(half8*)&a, *(half8*)&bf, accO, 0, 0, 0);
        else        accE = __builtin_amdgcn_mfma_f32_32x32x16_f16(*(half8*)&a, *(half8*)&bf, accE, 0, 0, 0);
      }
    }
  }
  f32x16 acc = accE + accO;

  int o = lane & 31;
  __syncthreads();
  if (kh == 0){
    #pragma unroll
    for (int r=0;r<16;r++){
      int pxl = mw*32 + ((r&3) + 8*(r>>2) + 4*half);
      if (o < NOFF) pivf[pxl][o] = acc[r];
    }
  }
  __syncthreads();
  if (kh == 1){
    #pragma unroll
    for (int r=0;r<16;r++){
      int pxl = mw*32 + ((r&3) + 8*(r>>2) + 4*half);
      if (o < NOFF) pivf[pxl][o] += acc[r];
    }
  }
  __syncthreads();

  if (tid < 64){
    int wpx = wh*64 + tid;               // image col
    float v[NOFF];
    #pragma unroll
    for (int oo=0;oo<NOFF;oo++) v[oo] = pivf[tid][oo] + b_off[oo];

    u32 rec[36];
    #pragma unroll
    for (int kk=0;kk<9;kk++){
      float py = (float)(h + kk/3 - 1) + v[2*kk];
      float qx = (float)(wpx + kk%3 - 1) + v[2*kk+1];
      float fy = floorf(py), fx = floorf(qx);
      float ty = py - fy, tx = qx - fx;
      int y0 = (int)fy, x0 = (int)fx;
      int y1 = y0+1, x1 = x0+1;
      bool vy0 = (y0>=0)&&(y0<Hh), vy1=(y1>=0)&&(y1<Hh);
      bool vx0 = (x0>=0)&&(x0<Ww), vx1=(x1>=0)&&(x1<Ww);
      u32 yc0 = (u32)(min(max(y0,0),Hh-1)*Ww), yc1 = (u32)(min(max(y1,0),Hh-1)*Ww);
      u32 xc0 = (u32)min(max(x0,0),Ww-1),      xc1 = (u32)min(max(x1,0),Ww-1);
      rec[2*kk]   = (yc0+xc0) | ((yc0+xc1)<<16);
      rec[2*kk+1] = (yc1+xc0) | ((yc1+xc1)<<16);
      float c00 = (vy0&&vx0) ? (1.f-ty)*(1.f-tx) : 0.f;
      float c01 = (vy0&&vx1) ? (1.f-ty)*tx       : 0.f;
      float c10 = (vy1&&vx0) ? ty*(1.f-tx)       : 0.f;
      float c11 = (vy1&&vx1) ? ty*tx             : 0.f;
      rec[18+2*kk] = pack2h(c00, c01);
      rec[19+2*kk] = pack2h(c10, c11);
    }
    int pxg = b*HW + h*Ww + wpx;
    uint4* dst = (uint4*)(recs + (size_t)pxg*36);
    #pragma unroll
    for (int q=0;q<9;q++) dst[q] = *(uint4*)(rec + q*4);
  }
}

// ---------------- K2: deformable depthwise — packed-f16 bilinear, fused stats ----------------
template<bool F16OUT>
__global__ __launch_bounds__(256) void k_deform_rec(const u32* __restrict__ xt, const u32* __restrict__ recs,
                                                    const u32* __restrict__ wdt_h, float* __restrict__ out,
                                                    u32* __restrict__ dwb, float* __restrict__ bps){
  __shared__ float pivot[16][132];
  int tid = threadIdx.x, lane = tid & 63, wid = tid >> 6;
  int pxb = blockIdx.x * 16;
  int bu = pxb >> 14, hw0 = pxb & 16383;
  int l2 = lane*2;

  __half2 wk2[9];
  #pragma unroll
  for (int k=0;k<9;k++){
    u32 wv = wdt_h[k*64 + lane];
    wk2[k] = *(__half2*)&wv;
  }

  const u32* xbu = xt + (size_t)bu*HW*64;

  #pragma unroll
  for (int i=0;i<4;i++){
    int pu = __builtin_amdgcn_readfirstlane(pxb + wid*4 + i);
    const u32* rec = recs + (size_t)pu*36;

    u32 q[9][4];
    #pragma unroll
    for (int kk=0;kk<9;kk++){
      u32 dA = rec[2*kk], dB = rec[2*kk+1];
      q[kk][0] = xbu[(size_t)(dA & 0xFFFFu)*64 + lane];
      q[kk][1] = xbu[(size_t)(dA >> 16)   *64 + lane];
      q[kk][2] = xbu[(size_t)(dB & 0xFFFFu)*64 + lane];
      q[kk][3] = xbu[(size_t)(dB >> 16)   *64 + lane];
    }

    __half2 acc2 = __floats2half2_rn(0.f, 0.f);
    #pragma unroll
    for (int kk=0;kk<9;kk++){
      u32 uA = rec[18+2*kk], uB = rec[19+2*kk];
      __half2 hA = *(__half2*)&uA, hB = *(__half2*)&uB;
      __half2 q0 = *(__half2*)&q[kk][0], q1 = *(__half2*)&q[kk][1];
      __half2 q2 = *(__half2*)&q[kk][2], q3 = *(__half2*)&q[kk][3];
      __half2 s = __hmul2(__low2half2(hA), q0);
      s = __hfma2(__high2half2(hA), q1, s);
      s = __hfma2(__low2half2(hB),  q2, s);
      s = __hfma2(__high2half2(hB), q3, s);
      acc2 = __hfma2(wk2[kk], s, acc2);
    }
    pivot[wid*4+i][l2]   = __low2float(acc2);
    pivot[wid*4+i][l2+1] = __high2float(acc2);
  }
  __syncthreads();
  #pragma unroll
  for (int it=0; it<2; it++){
    int c = (tid>>2) + it*64, qd = tid & 3;
    float4 r = make_float4(pivot[qd*4+0][c], pivot[qd*4+1][c], pivot[qd*4+2][c], pivot[qd*4+3][c]);
    float s  = (r.x + r.y) + (r.z + r.w);
    float s2 = fmaf(r.x,r.x, fmaf(r.y,r.y, fmaf(r.z,r.z, r.w*r.w)));
    s  += __shfl_down(s, 2, 4);  s  += __shfl_down(s, 1, 4);
    s2 += __shfl_down(s2, 2, 4); s2 += __shfl_down(s2, 1, 4);
    if (qd == 0){
      bps[(size_t)blockIdx.x*256 + c]       = s;
      bps[(size_t)blockIdx.x*256 + 128 + c] = s2;
    }
    if (F16OUT){
      uint2 pp; pp.x = pack2h(r.x, r.y); pp.y = pack2h(r.z, r.w);
      *(uint2*)&dwb[(((size_t)bu*Cc + c)*HW + hw0)/2 + qd*2] = pp;
    } else {
      *(float4*)(out + ((size_t)bu*Cc + c)*HW + hw0 + qd*4) = r;
    }
  }
}

// ---------------- stats reduce ----------------
__global__ __launch_bounds__(256) void k_statsr1(const float* __restrict__ bps, float* __restrict__ part2){
  int tid = threadIdx.x;
  size_t base = (size_t)blockIdx.x * 64;
  float a = 0.f;
  for (int r=0;r<64;r++) a += bps[(base + r)*256 + tid];
  part2[blockIdx.x*256 + tid] = a;
}

__global__ __launch_bounds__(256) void k_statsr2(const float* __restrict__ part2, float* __restrict__ mr){
  __shared__ float t[256];
  int tid = threadIdx.x;
  float a = 0.f;
  for (int r=0;r<128;r++) a += part2[r*256 + tid];
  t[tid] = a;
  __syncthreads();
  if (tid < 128){
    float S = t[tid], S2 = t[128 + tid];
    const float invN = 1.f/(float)(Bb*HW);
    float m = S*invN;
    float var = S2*invN - m*m;
    mr[tid]       = m;
    mr[Cc + tid]  = rsqrtf(var + 1e-5f);
  }
}

// ---------------- apply: BN + SiLU + residual ----------------
__global__ __launch_bounds__(256) void k_apply_f32(float* __restrict__ out, const float* __restrict__ x,
                                                   const float* __restrict__ mr, const float* __restrict__ gamma,
                                                   const float* __restrict__ beta){
  int i = blockIdx.x*256 + threadIdx.x;
  int c = (i >> 12) & 127;
  float4 v  = ((const float4*)out)[i];
  float4 xi = ((const float4*)x)[i];
  float m = mr[c], r = mr[Cc+c], g = gamma[c], be = beta[c];
  float* vp = (float*)&v; const float* xp = (const float*)&xi;
  float4 o; float* op = (float*)&o;
  #pragma unroll
  for (int j=0;j<4;j++){
    float t = (vp[j]-m)*r*g + be;
    t = t / (1.f + expf(-t));
    op[j] = t + xp[j];
  }
  ((float4*)out)[i] = o;
}

__global__ __launch_bounds__(256) void k_apply_f16(const u32* __restrict__ dwb, float* __restrict__ out,
                                                   const float* __restrict__ x, const float* __restrict__ mr,
                                                   const float* __restrict__ gamma, const float* __restrict__ beta){
  int i = blockIdx.x*256 + threadIdx.x;
  int c = (i >> 12) & 127;
  uint2 dw = ((const uint2*)dwb)[i];
  float4 xi = ((const float4*)x)[i];
  float m = mr[c], r = mr[Cc+c], g = gamma[c], be = beta[c];
  __half2 d0 = *(__half2*)&dw.x, d1 = *(__half2*)&dw.y;
  float v[4];
  v[0] = __low2float(d0); v[1] = __high2float(d0);
  v[2] = __low2float(d1); v[3] = __high2float(d1);
  const float* xp = (const float*)&xi;
  float4 o; float* op = (float*)&o;
  #pragma unroll
  for (int j=0;j<4;j++){
    float t = (v[j]-m)*r*g + be;
    t = t / (1.f + expf(-t));
    op[j] = t + xp[j];
  }
  ((float4*)out)[i] = o;
}

extern "C" void kernel_launch(void* const* d_in, const int* in_sizes, int n_in,
                              void* d_out, int out_size, void* d_ws, size_t ws_size,
                              hipStream_t stream) {
  const float* x     = (const float*)d_in[0];
  const float* w_off = (const float*)d_in[1];
  const float* b_off = (const float*)d_in[2];
  const float* w_dw  = (const float*)d_in[3];
  const float* gamma = (const float*)d_in[4];
  const float* beta  = (const float*)d_in[5];
  float* out = (float*)d_out;

  u32*   wBf  = (u32*)d_ws;                            // 18432
  u32*   wdt_h= (u32*)d_ws + 23040;                    // 576
  float* mr   = (float*)d_ws + 24576;                  // 256
  u32*   recs = (u32*)d_ws + 32768;                    // NPIX*36
  u32*   xt16 = recs + (size_t)NPIX*36;                // NPIX*64
  float* bps  = (float*)(xt16 + (size_t)NPIX*64);      // 8192*256
  float* part2= bps + (size_t)8192*256;                // 128*256
  u32*   dwb  = (u32*)(part2 + 128*256);               // NPIX*64 (f16 out_dw), big path only

  const size_t NEED_B = ((size_t)32768 + (size_t)NPIX*36 + (size_t)NPIX*64
                         + (size_t)8192*256 + 128*256 + (size_t)NPIX*64) * 4;
  bool big = (ws_size >= NEED_B);

  hipLaunchKernelGGL(k_repack, dim3((72*64*4 + 9*64 + 255)/256), dim3(256), 0, stream, w_off, w_dw, wBf, wdt_h);
  hipLaunchKernelGGL(k_tx,     dim3(2048), dim3(256), 0, stream, x, xt16);
  hipLaunchKernelGGL(k_offset_mfma, dim3(2048), dim3(256), 0, stream, xt16, wBf, b_off, recs);

  if (big){
    hipLaunchKernelGGL((k_deform_rec<true>), dim3(NPIX/16), dim3(256), 0, stream, xt16, recs, wdt_h, out, dwb, bps);
  } else {
    hipLaunchKernelGGL((k_deform_rec<false>), dim3(NPIX/16), dim3(256), 0, stream, xt16, recs, wdt_h, out, dwb, bps);
  }
  hipLaunchKernelGGL(k_statsr1, dim3(128), dim3(256), 0, stream, bps, part2);
  hipLaunchKernelGGL(k_statsr2, dim3(1),   dim3(256), 0, stream, part2, mr);
  if (big){
    hipLaunchKernelGGL(k_apply_f16, dim3(NPIX*Cc/4/256), dim3(256), 0, stream, dwb, out, x, mr, gamma, beta);
  } else {
    hipLaunchKernelGGL(k_apply_f32, dim3(NPIX*Cc/4/256), dim3(256), 0, stream, out, x, mr, gamma, beta);
  }
}

// Round 19
// 155.708 us; speedup vs baseline: 1.0160x; 1.0160x over previous
//
#include <hip/hip_runtime.h>
#include <hip/hip_fp16.h>
#include <math.h>

#define Cc 128
#define Hh 128
#define Ww 128
#define Bb 8
#define HW 16384
#define NPIX 131072   // B*H*W
#define NOFF 18

typedef unsigned int u32;
typedef _Float16 half8 __attribute__((ext_vector_type(8)));
typedef __attribute__((ext_vector_type(16))) float f32x16;

static __device__ __forceinline__ u32 pack2h(float a, float b){
  __half2 h = __floats2half2_rn(a, b);
  return *(u32*)&h;
}

// ---------------- K0: pack B-fragments (f16) + w_dw packed half2 [k][cpair] ----------------
__global__ __launch_bounds__(256) void k_repack(const float* __restrict__ w_off, const float* __restrict__ w_dw,
                                                u32* __restrict__ wBf, u32* __restrict__ wdt_h){
  int i = blockIdx.x*256 + threadIdx.x;
  if (i < 72*64*4){
    int step = i >> 8;
    int r    = i & 255;
    int lane = r >> 2;
    int q    = r & 3;
    int tap  = step / 8, chunk = step % 8;
    int o    = lane & 31, half = lane >> 5;
    int c0   = chunk*16 + half*8 + 2*q;
    float v0 = (o < NOFF) ? w_off[(size_t)(o*Cc + c0    )*9 + tap] : 0.f;
    float v1 = (o < NOFF) ? w_off[(size_t)(o*Cc + c0 + 1)*9 + tap] : 0.f;
    wBf[i] = pack2h(v0, v1);
  }
  int j = i - 72*64*4;
  if (j >= 0 && j < 9*64){
    int cp = j & 63; int k = j >> 6;
    wdt_h[j] = pack2h(w_dw[(2*cp)*9 + k], w_dw[(2*cp+1)*9 + k]);
  }
}

// ---------------- K_tx: transpose x NCHW -> NHWC, f16-packed (2 ch per u32) ----------------
__global__ __launch_bounds__(256) void k_tx(const float* __restrict__ x, u32* __restrict__ xt16){
  __shared__ float t[128][65];
  int tid = threadIdx.x;
  int b   = blockIdx.x >> 8;
  int hw0 = (blockIdx.x & 255) << 6;
  int lane = tid & 63, wg = tid >> 6;
  const float* xb = x + (size_t)b*Cc*HW;
  #pragma unroll
  for (int k=0;k<32;k++){
    int c = wg + k*4;
    t[c][lane] = xb[(size_t)c*HW + hw0 + lane];
  }
  __syncthreads();
  u32* ob = xt16 + ((size_t)b*HW + hw0)*64;
  int cpair = tid & 63, grp = tid >> 6;
  #pragma unroll
  for (int k=0;k<16;k++){
    int hwl = grp + k*4;
    ob[(size_t)hwl*64 + cpair] = pack2h(t[cpair*2][hwl], t[cpair*2+1][hwl]);
  }
}

// ---------------- K1: offset conv via f16 MFMA, row-at-a-time LDS staging (R17 best) ----------------
// grid 1024 = [b(8)][h(128)]; block 256 = 4 waves, each a 32-px M-tile (full 128-px row).
// Per r in {h-1,h,h+1}: stage 132-px halo'd row (34.3 KB, 65-dw px stride) -> 3 taps x 8 MFMA.
__global__ __launch_bounds__(256) void k_offset_mfma(const u32* __restrict__ xt, const u32* __restrict__ wBf,
                                                     const float* __restrict__ b_off, u32* __restrict__ recs){
  __shared__ u32 xl[132][65];            // 34.3 KB; piv [128][21] overlays after MFMA
  int tid = threadIdx.x, lane = tid & 63, wv = tid >> 6;
  int b = blockIdx.x >> 7, h = blockIdx.x & 127;
  int row = lane & 31, half = lane >> 5;
  int w = wv*32 + row;

  const u32* xb = xt + (size_t)b*HW*64;
  const uint4* wb = (const uint4*)wBf;

  f32x16 accE, accO;
  #pragma unroll
  for (int i=0;i<16;i++){ accE[i]=0.f; accO[i]=0.f; }

  const u32* xl0 = &xl[0][0];

  #pragma unroll 1
  for (int r=0; r<3; r++){
    int hh = h + r - 1;
    int hc = min(max(hh,0),Hh-1);
    __syncthreads();                     // previous phase's readers done
    for (int i=tid; i<132*16; i+=256){
      int q = i & 15, p = i >> 4;
      int gc = min(max(p-2, 0), Ww-1);
      *(uint4*)&xl[p][q*4] = *(const uint4*)(xb + ((size_t)(hc*Ww + gc))*64 + q*4);
    }
    __syncthreads();
    bool rowv = (hh>=0)&&(hh<Hh);
    #pragma unroll
    for (int dx=0; dx<3; dx++){
      int t = r*3 + dx;
      int wt = w + dx - 1;
      bool v = rowv && (wt>=0)&&(wt<Ww);
      int base = (w + dx + 1)*65 + half*4;     // p = (w+dx-1)+2
      #pragma unroll
      for (int ch=0; ch<8; ch++){
        uint4 a = *(const uint4*)(xl0 + base + ch*8);
        if (!v){ a.x=0u; a.y=0u; a.z=0u; a.w=0u; }
        uint4 bf = wb[(t*8+ch)*64 + lane];
        if (ch & 1) accO = __builtin_amdgcn_mfma_f32_32x32x16_f16(*(half8*)&a, *(half8*)&bf, accO, 0, 0, 0);
        else        accE = __builtin_amdgcn_mfma_f32_32x32x16_f16(*(half8*)&a, *(half8*)&bf, accE, 0, 0, 0);
      }
    }
  }
  f32x16 acc = accE + accO;

  __syncthreads();                       // xl reads done; overlay piv
  float* pivf = (float*)&xl[0][0];
  int o = lane & 31;
  #pragma unroll
  for (int r=0;r<16;r++){
    int pxl = wv*32 + ((r&3) + 8*(r>>2) + 4*half);
    if (o < NOFF) pivf[pxl*21 + o] = acc[r];
  }
  __syncthreads();

  if (tid < 128){
    int wpx = tid;
    float v[NOFF];
    #pragma unroll
    for (int oo=0;oo<NOFF;oo++) v[oo] = pivf[tid*21 + oo] + b_off[oo];

    u32 rec[36];
    #pragma unroll
    for (int kk=0;kk<9;kk++){
      float py = (float)(h + kk/3 - 1) + v[2*kk];
      float qx = (float)(wpx + kk%3 - 1) + v[2*kk+1];
      float fy = floorf(py), fx = floorf(qx);
      float ty = py - fy, tx = qx - fx;
      int y0 = (int)fy, x0 = (int)fx;
      int y1 = y0+1, x1 = x0+1;
      bool vy0 = (y0>=0)&&(y0<Hh), vy1=(y1>=0)&&(y1<Hh);
      bool vx0 = (x0>=0)&&(x0<Ww), vx1=(x1>=0)&&(x1<Ww);
      u32 yc0 = (u32)(min(max(y0,0),Hh-1)*Ww), yc1 = (u32)(min(max(y1,0),Hh-1)*Ww);
      u32 xc0 = (u32)min(max(x0,0),Ww-1),      xc1 = (u32)min(max(x1,0),Ww-1);
      rec[2*kk]   = (yc0+xc0) | ((yc0+xc1)<<16);
      rec[2*kk+1] = (yc1+xc0) | ((yc1+xc1)<<16);
      float c00 = (vy0&&vx0) ? (1.f-ty)*(1.f-tx) : 0.f;
      float c01 = (vy0&&vx1) ? (1.f-ty)*tx       : 0.f;
      float c10 = (vy1&&vx0) ? ty*(1.f-tx)       : 0.f;
      float c11 = (vy1&&vx1) ? ty*tx             : 0.f;
      rec[18+2*kk] = pack2h(c00, c01);
      rec[19+2*kk] = pack2h(c10, c11);
    }
    int pxg = b*HW + h*Ww + wpx;
    uint4* dst = (uint4*)(recs + (size_t)pxg*36);
    #pragma unroll
    for (int q=0;q<9;q++) dst[q] = *(uint4*)(rec + q*4);
  }
}

// ---------------- K2: deformable depthwise — packed-f16 bilinear, fused stats ----------------
template<bool F16OUT>
__global__ __launch_bounds__(256) void k_deform_rec(const u32* __restrict__ xt, const u32* __restrict__ recs,
                                                    const u32* __restrict__ wdt_h, float* __restrict__ out,
                                                    u32* __restrict__ dwb, float* __restrict__ bps){
  __shared__ float pivot[16][132];
  int tid = threadIdx.x, lane = tid & 63, wid = tid >> 6;
  int pxb = blockIdx.x * 16;
  int bu = pxb >> 14, hw0 = pxb & 16383;
  int l2 = lane*2;

  __half2 wk2[9];
  #pragma unroll
  for (int k=0;k<9;k++){
    u32 wv = wdt_h[k*64 + lane];
    wk2[k] = *(__half2*)&wv;
  }

  const u32* xbu = xt + (size_t)bu*HW*64;

  #pragma unroll
  for (int i=0;i<4;i++){
    int pu = __builtin_amdgcn_readfirstlane(pxb + wid*4 + i);
    const u32* rec = recs + (size_t)pu*36;

    u32 q[9][4];
    #pragma unroll
    for (int kk=0;kk<9;kk++){
      u32 dA = rec[2*kk], dB = rec[2*kk+1];
      q[kk][0] = xbu[(size_t)(dA & 0xFFFFu)*64 + lane];
      q[kk][1] = xbu[(size_t)(dA >> 16)   *64 + lane];
      q[kk][2] = xbu[(size_t)(dB & 0xFFFFu)*64 + lane];
      q[kk][3] = xbu[(size_t)(dB >> 16)   *64 + lane];
    }

    __half2 acc2 = __floats2half2_rn(0.f, 0.f);
    #pragma unroll
    for (int kk=0;kk<9;kk++){
      u32 uA = rec[18+2*kk], uB = rec[19+2*kk];
      __half2 hA = *(__half2*)&uA, hB = *(__half2*)&uB;
      __half2 q0 = *(__half2*)&q[kk][0], q1 = *(__half2*)&q[kk][1];
      __half2 q2 = *(__half2*)&q[kk][2], q3 = *(__half2*)&q[kk][3];
      __half2 s = __hmul2(__low2half2(hA), q0);
      s = __hfma2(__high2half2(hA), q1, s);
      s = __hfma2(__low2half2(hB),  q2, s);
      s = __hfma2(__high2half2(hB), q3, s);
      acc2 = __hfma2(wk2[kk], s, acc2);
    }
    pivot[wid*4+i][l2]   = __low2float(acc2);
    pivot[wid*4+i][l2+1] = __high2float(acc2);
  }
  __syncthreads();
  #pragma unroll
  for (int it=0; it<2; it++){
    int c = (tid>>2) + it*64, qd = tid & 3;
    float4 r = make_float4(pivot[qd*4+0][c], pivot[qd*4+1][c], pivot[qd*4+2][c], pivot[qd*4+3][c]);
    float s  = (r.x + r.y) + (r.z + r.w);
    float s2 = fmaf(r.x,r.x, fmaf(r.y,r.y, fmaf(r.z,r.z, r.w*r.w)));
    s  += __shfl_down(s, 2, 4);  s  += __shfl_down(s, 1, 4);
    s2 += __shfl_down(s2, 2, 4); s2 += __shfl_down(s2, 1, 4);
    if (qd == 0){
      bps[(size_t)blockIdx.x*256 + c]       = s;
      bps[(size_t)blockIdx.x*256 + 128 + c] = s2;
    }
    if (F16OUT){
      uint2 pp; pp.x = pack2h(r.x, r.y); pp.y = pack2h(r.z, r.w);
      *(uint2*)&dwb[(((size_t)bu*Cc + c)*HW + hw0)/2 + qd*2] = pp;
    } else {
      *(float4*)(out + ((size_t)bu*Cc + c)*HW + hw0 + qd*4) = r;
    }
  }
}

// ---------------- stats reduce ----------------
__global__ __launch_bounds__(256) void k_statsr1(const float* __restrict__ bps, float* __restrict__ part2){
  int tid = threadIdx.x;
  size_t base = (size_t)blockIdx.x * 64;
  float a = 0.f;
  for (int r=0;r<64;r++) a += bps[(base + r)*256 + tid];
  part2[blockIdx.x*256 + tid] = a;
}

__global__ __launch_bounds__(256) void k_statsr2(const float* __restrict__ part2, float* __restrict__ mr){
  __shared__ float t[256];
  int tid = threadIdx.x;
  float a = 0.f;
  for (int r=0;r<128;r++) a += part2[r*256 + tid];
  t[tid] = a;
  __syncthreads();
  if (tid < 128){
    float S = t[tid], S2 = t[128 + tid];
    const float invN = 1.f/(float)(Bb*HW);
    float m = S*invN;
    float var = S2*invN - m*m;
    mr[tid]       = m;
    mr[Cc + tid]  = rsqrtf(var + 1e-5f);
  }
}

// ---------------- apply: BN + SiLU + residual ----------------
__global__ __launch_bounds__(256) void k_apply_f32(float* __restrict__ out, const float* __restrict__ x,
                                                   const float* __restrict__ mr, const float* __restrict__ gamma,
                                                   const float* __restrict__ beta){
  int i = blockIdx.x*256 + threadIdx.x;
  int c = (i >> 12) & 127;
  float4 v  = ((const float4*)out)[i];
  float4 xi = ((const float4*)x)[i];
  float m = mr[c], r = mr[Cc+c], g = gamma[c], be = beta[c];
  float* vp = (float*)&v; const float* xp = (const float*)&xi;
  float4 o; float* op = (float*)&o;
  #pragma unroll
  for (int j=0;j<4;j++){
    float t = (vp[j]-m)*r*g + be;
    t = t / (1.f + expf(-t));
    op[j] = t + xp[j];
  }
  ((float4*)out)[i] = o;
}

__global__ __launch_bounds__(256) void k_apply_f16(const u32* __restrict__ dwb, float* __restrict__ out,
                                                   const float* __restrict__ x, const float* __restrict__ mr,
                                                   const float* __restrict__ gamma, const float* __restrict__ beta){
  int i = blockIdx.x*256 + threadIdx.x;
  int c = (i >> 12) & 127;
  uint2 dw = ((const uint2*)dwb)[i];
  float4 xi = ((const float4*)x)[i];
  float m = mr[c], r = mr[Cc+c], g = gamma[c], be = beta[c];
  __half2 d0 = *(__half2*)&dw.x, d1 = *(__half2*)&dw.y;
  float v[4];
  v[0] = __low2float(d0); v[1] = __high2float(d0);
  v[2] = __low2float(d1); v[3] = __high2float(d1);
  const float* xp = (const float*)&xi;
  float4 o; float* op = (float*)&o;
  #pragma unroll
  for (int j=0;j<4;j++){
    float t = (v[j]-m)*r*g + be;
    t = t / (1.f + expf(-t));
    op[j] = t + xp[j];
  }
  ((float4*)out)[i] = o;
}

extern "C" void kernel_launch(void* const* d_in, const int* in_sizes, int n_in,
                              void* d_out, int out_size, void* d_ws, size_t ws_size,
                              hipStream_t stream) {
  const float* x     = (const float*)d_in[0];
  const float* w_off = (const float*)d_in[1];
  const float* b_off = (const float*)d_in[2];
  const float* w_dw  = (const float*)d_in[3];
  const float* gamma = (const float*)d_in[4];
  const float* beta  = (const float*)d_in[5];
  float* out = (float*)d_out;

  u32*   wBf  = (u32*)d_ws;                            // 18432
  u32*   wdt_h= (u32*)d_ws + 23040;                    // 576
  float* mr   = (float*)d_ws + 24576;                  // 256
  u32*   recs = (u32*)d_ws + 32768;                    // NPIX*36
  u32*   xt16 = recs + (size_t)NPIX*36;                // NPIX*64
  float* bps  = (float*)(xt16 + (size_t)NPIX*64);      // 8192*256
  float* part2= bps + (size_t)8192*256;                // 128*256
  u32*   dwb  = (u32*)(part2 + 128*256);               // NPIX*64 (f16 out_dw), big path only

  const size_t NEED_B = ((size_t)32768 + (size_t)NPIX*36 + (size_t)NPIX*64
                         + (size_t)8192*256 + 128*256 + (size_t)NPIX*64) * 4;
  bool big = (ws_size >= NEED_B);

  hipLaunchKernelGGL(k_repack, dim3((72*64*4 + 9*64 + 255)/256), dim3(256), 0, stream, w_off, w_dw, wBf, wdt_h);
  hipLaunchKernelGGL(k_tx,     dim3(2048), dim3(256), 0, stream, x, xt16);
  hipLaunchKernelGGL(k_offset_mfma, dim3(1024), dim3(256), 0, stream, xt16, wBf, b_off, recs);

  if (big){
    hipLaunchKernelGGL((k_deform_rec<true>), dim3(NPIX/16), dim3(256), 0, stream, xt16, recs, wdt_h, out, dwb, bps);
  } else {
    hipLaunchKernelGGL((k_deform_rec<false>), dim3(NPIX/16), dim3(256), 0, stream, xt16, recs, wdt_h, out, dwb, bps);
  }
  hipLaunchKernelGGL(k_statsr1, dim3(128), dim3(256), 0, stream, bps, part2);
  hipLaunchKernelGGL(k_statsr2, dim3(1),   dim3(256), 0, stream, part2, mr);
  if (big){
    hipLaunchKernelGGL(k_apply_f16, dim3(NPIX*Cc/4/256), dim3(256), 0, stream, dwb, out, x, mr, gamma, beta);
  } else {
    hipLaunchKernelGGL(k_apply_f32, dim3(NPIX*Cc/4/256), dim3(256), 0, stream, out, x, mr, gamma, beta);
  }
}